// Round 6
// baseline (207.885 us; speedup 1.0000x reference)
//
#include <hip/hip_runtime.h>

// Problem constants (fixed by setup_inputs)
constexpr int T_TASKS = 256;
constexpr int NQ      = 300;
constexpr int NS      = 25;
constexpr int D       = 640;
constexpr int NWAY    = 5;
constexpr float LAMBDA_REG = 50.0f;

constexpr int SP4 = 161;        // float4 stride of one S row in LDS (644 floats)
constexpr int NT  = 1024;       // threads per block (16 waves)
constexpr int AC  = NS + NWAY;  // augmented columns = 30
constexpr int HALF_ROWS = 150;  // query rows per block (2 blocks per task)

// Pair-block table: 15 upper-triangle 5x5 blocks of the 25x25 Gram matrix
__device__ __constant__ int PA[15] = {0,0,0,0,0,1,1,1,1,2,2,2,3,3,4};
__device__ __constant__ int PB[15] = {0,1,2,3,4,1,2,3,4,2,3,4,3,4,4};

// ---------------------------------------------------------------------------
// Fused per-task kernel, TWO blocks per task (each owns 150 query rows).
// Design point: 64 VGPRs (the allocator's hard target on this toolchain for
// 1024-thread blocks), 2 blocks/CU (LDS 80,900B x2 fits 160KB), 32 waves/CU.
// R3-R5 lesson: anything with >64 live regs (5-row fusion, cross-barrier
// prefetch) spills to scratch and runs 3x slower. So: 3-row fusion (~40 live
// regs), no cross-barrier prefetch, exec-masked tail loads (no clamp traffic).
// ---------------------------------------------------------------------------
__global__ __launch_bounds__(NT) void fused_ridge_head_kernel(
    const float* __restrict__ query,    // (T, NQ, D)
    const float* __restrict__ support,  // (T, NS, D)
    const float* __restrict__ scale,    // (1,)
    const int*   __restrict__ labels,   // (T, NS)
    float*       __restrict__ out)      // (T, NQ, NWAY)
{
    __shared__ __align__(16) float4 sS4[NS * SP4];   // 64,400 B
    __shared__ __align__(16) float  sW[NWAY][D];     // 12,800 B
    __shared__ float aug[NS][32];                    //  3,200 B
    __shared__ float sX[NS][NWAY];                   //    500 B  => 80,900 B

    const int blk  = blockIdx.x;
    const int t    = blk >> 1;
    const int half = blk & 1;
    const int tid  = threadIdx.x;
    const float* Sg    = support + (size_t)t * NS * D;
    const float* Qbase = query   + (size_t)t * NQ * D;
    const float sc = scale[0];

    // ---- A1: stage S into LDS (coalesced float4) + RHS init ----------------
    for (int idx = tid; idx < NS * 160; idx += NT) {
        int s = idx / 160, f = idx % 160;
        sS4[s * SP4 + f] = reinterpret_cast<const float4*>(Sg)[idx];
    }
    if (tid >= 960) {                       // wave 15: RHS = 2 * onehot
        for (int idx = tid - 960; idx < NS * NWAY; idx += 64) {
            int s = idx / NWAY, w = idx % NWAY;
            aug[s][NS + w] = (labels[t * NS + s] == w) ? 2.0f : 0.0f;
        }
    }
    __syncthreads();

    // ---- A2: K = S S^T + lambda I, 5x5 register-blocked (waves 0..3) -------
    // B row reloaded per-j to keep peak pressure ~55 regs (<=64).
    if (tid < 240) {
        const int grp = tid >> 4, l = tid & 15;
        const int ra = PA[grp] * 5, rb = PB[grp] * 5;
        float acc[25] = {};
        #pragma unroll
        for (int k = 0; k < 10; ++k) {
            const int f = l + 16 * k;
            float4 A[5];
            #pragma unroll
            for (int r = 0; r < 5; ++r) A[r] = sS4[(ra + r) * SP4 + f];
            #pragma unroll
            for (int j = 0; j < 5; ++j) {
                float4 b = sS4[(rb + j) * SP4 + f];
                #pragma unroll
                for (int i = 0; i < 5; ++i)
                    acc[i * 5 + j] += A[i].x * b.x + A[i].y * b.y +
                                      A[i].z * b.z + A[i].w * b.w;
            }
        }
        #pragma unroll
        for (int p = 0; p < 25; ++p) {
            #pragma unroll
            for (int off = 8; off >= 1; off >>= 1)
                acc[p] += __shfl_xor(acc[p], off);
        }
        if (l == 0) {
            #pragma unroll
            for (int p = 0; p < 25; ++p) {
                int i = ra + p / 5, j = rb + p % 5;
                float v = acc[p] + (i == j ? LAMBDA_REG : 0.0f);
                aug[i][j] = v;
                aug[j][i] = v;
            }
        }
    }
    __syncthreads();

    // ---- A3 (wave 0): Gauss-Jordan in registers -> X into LDS --------------
    if (tid < 64) {
        const int  c      = tid;
        const bool active = (c < AC);
        float a[NS];
        #pragma unroll
        for (int r = 0; r < NS; ++r) a[r] = active ? aug[r][c] : 0.0f;
        #pragma unroll
        for (int k = 0; k < NS; ++k) {
            float piv = __shfl(a[k], k);    // aug[k][k]
            float inv = 1.0f / piv;
            a[k] *= inv;
            #pragma unroll
            for (int r = 0; r < NS; ++r) {
                if (r != k) {
                    float m = __shfl(a[r], k);
                    a[r] -= m * a[k];
                }
            }
        }
        if (active && c >= NS) {            // RHS columns now hold X = 2 K^-1 Y
            const int w = c - NS;
            #pragma unroll
            for (int s = 0; s < NS; ++s) sX[s][w] = a[s];
        }
    }
    __syncthreads();

    // ---- A4: W[w][d] = sum_s S[s][d] * X[s][w]  (tid < 640) ----------------
    if (tid < D) {
        const float* sSf = reinterpret_cast<const float*>(sS4);
        float acc[NWAY] = {};
        #pragma unroll
        for (int s = 0; s < NS; ++s) {
            float sv = sSf[s * (SP4 * 4) + tid];
            #pragma unroll
            for (int w = 0; w < NWAY; ++w) acc[w] += sv * sX[s][w];
        }
        #pragma unroll
        for (int w = 0; w < NWAY; ++w) sW[w][tid] = acc[w];
    }
    __syncthreads();

    // ---- Phase B: logits = scale * Q W, 3 rows per 16-lane group -----------
    // Block owns rows [half*150, half*150+150): group g -> g, g+64, g+128(g<22)
    const int g  = tid >> 4;
    const int l4 = tid & 15;
    const int q0 = half * HALF_ROWS + g;
    const bool v2 = (g < HALF_ROWS - 128);          // g < 22
    const float4* Qb4 = reinterpret_cast<const float4*>(Qbase);
    const int off0 = q0 * 160 + l4;

    float acc0[NWAY] = {}, acc1[NWAY] = {}, acc2[NWAY] = {};

    #pragma unroll
    for (int i = 0; i < 10; ++i) {
        float4 qv0 = Qb4[off0 + i * 16];
        float4 qv1 = Qb4[off0 + 64 * 160 + i * 16];
        float4 qv2 = make_float4(0.f, 0.f, 0.f, 0.f);
        if (v2) qv2 = Qb4[off0 + 128 * 160 + i * 16];   // exec-masked: no
                                                        // traffic for g>=22
        const int dbase = i * 64 + 4 * l4;
        #pragma unroll
        for (int w = 0; w < NWAY; ++w) {
            const float4 wv = *reinterpret_cast<const float4*>(&sW[w][dbase]);
            acc0[w] += qv0.x * wv.x + qv0.y * wv.y + qv0.z * wv.z + qv0.w * wv.w;
            acc1[w] += qv1.x * wv.x + qv1.y * wv.y + qv1.z * wv.z + qv1.w * wv.w;
            acc2[w] += qv2.x * wv.x + qv2.y * wv.y + qv2.z * wv.z + qv2.w * wv.w;
        }
    }

    // Reduce across the 16-lane group; lanes 0..4 store one float each.
    #pragma unroll
    for (int w = 0; w < NWAY; ++w) {
        #pragma unroll
        for (int o = 8; o >= 1; o >>= 1) {
            acc0[w] += __shfl_xor(acc0[w], o);
            acc1[w] += __shfl_xor(acc1[w], o);
            acc2[w] += __shfl_xor(acc2[w], o);
        }
    }
    float ov0 = acc0[0], ov1 = acc1[0], ov2 = acc2[0];
    ov0 = (l4 == 1) ? acc0[1] : ov0;  ov1 = (l4 == 1) ? acc1[1] : ov1;  ov2 = (l4 == 1) ? acc2[1] : ov2;
    ov0 = (l4 == 2) ? acc0[2] : ov0;  ov1 = (l4 == 2) ? acc1[2] : ov1;  ov2 = (l4 == 2) ? acc2[2] : ov2;
    ov0 = (l4 == 3) ? acc0[3] : ov0;  ov1 = (l4 == 3) ? acc1[3] : ov1;  ov2 = (l4 == 3) ? acc2[3] : ov2;
    ov0 = (l4 == 4) ? acc0[4] : ov0;  ov1 = (l4 == 4) ? acc1[4] : ov1;  ov2 = (l4 == 4) ? acc2[4] : ov2;

    if (l4 < NWAY) {
        out[((size_t)t * NQ + q0) * NWAY + l4]        = sc * ov0;
        out[((size_t)t * NQ + q0 + 64) * NWAY + l4]   = sc * ov1;
        if (v2)
            out[((size_t)t * NQ + q0 + 128) * NWAY + l4] = sc * ov2;
    }
}

extern "C" void kernel_launch(void* const* d_in, const int* in_sizes, int n_in,
                              void* d_out, int out_size, void* d_ws, size_t ws_size,
                              hipStream_t stream) {
    const float* query   = (const float*)d_in[0];
    const float* support = (const float*)d_in[1];
    const float* scale   = (const float*)d_in[2];
    const int*   labels  = (const int*)d_in[3];
    float* out = (float*)d_out;

    fused_ridge_head_kernel<<<T_TASKS * 2, NT, 0, stream>>>(query, support, scale, labels, out);
}

// Round 7
// 57.674 us; speedup vs baseline: 3.6045x; 3.6045x over previous
//
#include <hip/hip_runtime.h>

// Problem constants (fixed by setup_inputs)
constexpr int T_TASKS = 256;
constexpr int NQ      = 300;
constexpr int NS      = 25;
constexpr int D       = 640;
constexpr int NWAY    = 5;
constexpr float LAMBDA_REG = 50.0f;

constexpr int SP4 = 161;        // float4 stride of one S row in LDS (644 floats)
constexpr int NT  = 1024;       // threads per block (16 waves)
constexpr int AC  = NS + NWAY;  // augmented columns = 30

// Pair-block table: 15 upper-triangle 5x5 blocks of the 25x25 Gram matrix
__device__ __constant__ int PA[15] = {0,0,0,0,0,1,1,1,1,2,2,2,3,3,4};
__device__ __constant__ int PB[15] = {0,1,2,3,4,1,2,3,4,2,3,4,3,4,4};

// ---------------------------------------------------------------------------
// Fused per-task kernel, one block per task (grid 256, 1 block/CU).
//
// HARD CONSTRAINT (R3-R6): for 1024-thread blocks this toolchain pins the
// VGPR target at 64 and will spill rather than expand. The dominant pressure
// source is NOT the accumulators but LOAD HOISTING: a fully-unrolled i-loop
// with R fused rows puts 10*R float4 loads in flight (40*R VGPRs). R6's
// 3-row full-unroll = 120 regs -> 374 MB of scratch writes -> 207us.
// Design rule here: rows_fused * unroll_depth * 4 <= ~24 in-flight regs.
// Phase B: pass A = 3 rows x unroll 2 (24 in-flight), pass B = 2 rows.
// W is still reused 3x/2x from LDS (~8us LDS issue vs R2's 20us).
// ---------------------------------------------------------------------------
__global__ __launch_bounds__(NT) void fused_ridge_head_kernel(
    const float* __restrict__ query,    // (T, NQ, D)
    const float* __restrict__ support,  // (T, NS, D)
    const float* __restrict__ scale,    // (1,)
    const int*   __restrict__ labels,   // (T, NS)
    float*       __restrict__ out)      // (T, NQ, NWAY)
{
    __shared__ __align__(16) float4 sS4[NS * SP4];   // 64,400 B
    __shared__ __align__(16) float  sW[NWAY][D];     // 12,800 B
    __shared__ float aug[NS][32];                    //  3,200 B
    __shared__ float sX[NS][NWAY];                   //    500 B  => 80,900 B

    const int t   = blockIdx.x;
    const int tid = threadIdx.x;
    const float* Sg    = support + (size_t)t * NS * D;
    const float* Qbase = query   + (size_t)t * NQ * D;
    const float sc = scale[0];

    // ---- A1: stage S into LDS (coalesced float4) + RHS init ----------------
    for (int idx = tid; idx < NS * 160; idx += NT) {
        int s = idx / 160, f = idx % 160;
        sS4[s * SP4 + f] = reinterpret_cast<const float4*>(Sg)[idx];
    }
    if (tid >= 960) {                       // wave 15: RHS = 2 * onehot
        for (int idx = tid - 960; idx < NS * NWAY; idx += 64) {
            int s = idx / NWAY, w = idx % NWAY;
            aug[s][NS + w] = (labels[t * NS + s] == w) ? 2.0f : 0.0f;
        }
    }
    __syncthreads();

    // ---- A2: K = S S^T + lambda I, 5x5 register-blocked (waves 0..3) -------
    // B row reloaded per-j: peak ~55 regs.
    if (tid < 240) {
        const int grp = tid >> 4, l = tid & 15;
        const int ra = PA[grp] * 5, rb = PB[grp] * 5;
        float acc[25] = {};
        #pragma unroll 2
        for (int k = 0; k < 10; ++k) {
            const int f = l + 16 * k;
            float4 A[5];
            #pragma unroll
            for (int r = 0; r < 5; ++r) A[r] = sS4[(ra + r) * SP4 + f];
            #pragma unroll
            for (int j = 0; j < 5; ++j) {
                float4 b = sS4[(rb + j) * SP4 + f];
                #pragma unroll
                for (int i = 0; i < 5; ++i)
                    acc[i * 5 + j] += A[i].x * b.x + A[i].y * b.y +
                                      A[i].z * b.z + A[i].w * b.w;
            }
        }
        #pragma unroll
        for (int p = 0; p < 25; ++p) {
            #pragma unroll
            for (int off = 8; off >= 1; off >>= 1)
                acc[p] += __shfl_xor(acc[p], off);
        }
        if (l == 0) {
            #pragma unroll
            for (int p = 0; p < 25; ++p) {
                int i = ra + p / 5, j = rb + p % 5;
                float v = acc[p] + (i == j ? LAMBDA_REG : 0.0f);
                aug[i][j] = v;
                aug[j][i] = v;
            }
        }
    }
    __syncthreads();

    // ---- A3 (wave 0): Gauss-Jordan in registers -> X into LDS --------------
    if (tid < 64) {
        const int  c      = tid;
        const bool active = (c < AC);
        float a[NS];
        #pragma unroll
        for (int r = 0; r < NS; ++r) a[r] = active ? aug[r][c] : 0.0f;
        #pragma unroll
        for (int k = 0; k < NS; ++k) {
            float piv = __shfl(a[k], k);    // aug[k][k]
            float inv = 1.0f / piv;
            a[k] *= inv;
            #pragma unroll
            for (int r = 0; r < NS; ++r) {
                if (r != k) {
                    float m = __shfl(a[r], k);
                    a[r] -= m * a[k];
                }
            }
        }
        if (active && c >= NS) {            // RHS columns now hold X = 2 K^-1 Y
            const int w = c - NS;
            #pragma unroll
            for (int s = 0; s < NS; ++s) sX[s][w] = a[s];
        }
    }
    __syncthreads();

    // ---- A4: W[w][d] = sum_s S[s][d] * X[s][w]  (tid < 640) ----------------
    if (tid < D) {
        const float* sSf = reinterpret_cast<const float*>(sS4);
        float acc[NWAY] = {};
        #pragma unroll
        for (int s = 0; s < NS; ++s) {
            float sv = sSf[s * (SP4 * 4) + tid];
            #pragma unroll
            for (int w = 0; w < NWAY; ++w) acc[w] += sv * sX[s][w];
        }
        #pragma unroll
        for (int w = 0; w < NWAY; ++w) sW[w][tid] = acc[w];
    }
    __syncthreads();

    // ---- Phase B: logits = scale * Q W --------------------------------------
    // Group g owns rows {g, g+64, g+128, g+192, g+256(g<44)}.
    const int g  = tid >> 4;
    const int l4 = tid & 15;
    const float4* Qb4 = reinterpret_cast<const float4*>(Qbase);

    // helper: reduce 16-lane group and store one row (lanes 0..4 write)
    auto reduce_store = [&](float acc[NWAY], int q) {
        #pragma unroll
        for (int w = 0; w < NWAY; ++w) {
            #pragma unroll
            for (int o = 8; o >= 1; o >>= 1)
                acc[w] += __shfl_xor(acc[w], o);
        }
        float ov = acc[0];
        ov = (l4 == 1) ? acc[1] : ov;
        ov = (l4 == 2) ? acc[2] : ov;
        ov = (l4 == 3) ? acc[3] : ov;
        ov = (l4 == 4) ? acc[4] : ov;
        if (l4 < NWAY)
            out[((size_t)t * NQ + q) * NWAY + l4] = sc * ov;
    };

    {   // ---- Pass A: rows g, g+64, g+128 (all < 300) -----------------------
        const int off0 = (g)       * 160 + l4;
        const int off1 = (g + 64)  * 160 + l4;
        const int off2 = (g + 128) * 160 + l4;
        float a0[NWAY] = {}, a1[NWAY] = {}, a2[NWAY] = {};
        #pragma unroll 2
        for (int i = 0; i < 10; ++i) {
            float4 q0 = Qb4[off0 + i * 16];
            float4 q1 = Qb4[off1 + i * 16];
            float4 q2 = Qb4[off2 + i * 16];
            const int dbase = i * 64 + 4 * l4;
            #pragma unroll
            for (int w = 0; w < NWAY; ++w) {
                const float4 wv = *reinterpret_cast<const float4*>(&sW[w][dbase]);
                a0[w] += q0.x * wv.x + q0.y * wv.y + q0.z * wv.z + q0.w * wv.w;
                a1[w] += q1.x * wv.x + q1.y * wv.y + q1.z * wv.z + q1.w * wv.w;
                a2[w] += q2.x * wv.x + q2.y * wv.y + q2.z * wv.z + q2.w * wv.w;
            }
        }
        reduce_store(a0, g);
        reduce_store(a1, g + 64);
        reduce_store(a2, g + 128);
    }

    {   // ---- Pass B: rows g+192, g+256 (latter only for g < 44) ------------
        const bool v1 = (g < NQ - 256);             // g < 44
        const int off0 = (g + 192) * 160 + l4;
        const int off1 = (g + 256) * 160 + l4;      // only read when v1
        float a0[NWAY] = {}, a1[NWAY] = {};
        #pragma unroll 2
        for (int i = 0; i < 10; ++i) {
            float4 q0 = Qb4[off0 + i * 16];
            float4 q1 = make_float4(0.f, 0.f, 0.f, 0.f);
            if (v1) q1 = Qb4[off1 + i * 16];        // exec-masked, no traffic
            const int dbase = i * 64 + 4 * l4;
            #pragma unroll
            for (int w = 0; w < NWAY; ++w) {
                const float4 wv = *reinterpret_cast<const float4*>(&sW[w][dbase]);
                a0[w] += q0.x * wv.x + q0.y * wv.y + q0.z * wv.z + q0.w * wv.w;
                a1[w] += q1.x * wv.x + q1.y * wv.y + q1.z * wv.z + q1.w * wv.w;
            }
        }
        reduce_store(a0, g + 192);
        #pragma unroll
        for (int w = 0; w < NWAY; ++w) {
            #pragma unroll
            for (int o = 8; o >= 1; o >>= 1)
                a1[w] += __shfl_xor(a1[w], o);
        }
        float ov = a1[0];
        ov = (l4 == 1) ? a1[1] : ov;
        ov = (l4 == 2) ? a1[2] : ov;
        ov = (l4 == 3) ? a1[3] : ov;
        ov = (l4 == 4) ? a1[4] : ov;
        if (v1 && l4 < NWAY)
            out[((size_t)t * NQ + g + 256) * NWAY + l4] = sc * ov;
    }
}

extern "C" void kernel_launch(void* const* d_in, const int* in_sizes, int n_in,
                              void* d_out, int out_size, void* d_ws, size_t ws_size,
                              hipStream_t stream) {
    const float* query   = (const float*)d_in[0];
    const float* support = (const float*)d_in[1];
    const float* scale   = (const float*)d_in[2];
    const int*   labels  = (const int*)d_in[3];
    float* out = (float*)d_out;

    fused_ridge_head_kernel<<<T_TASKS, NT, 0, stream>>>(query, support, scale, labels, out);
}